// Round 2
// baseline (523.636 us; speedup 1.0000x reference)
//
#include <hip/hip_runtime.h>
#include <math.h>

#define EPS  1e-5f
#define EPS2 1e-10f
#define MAXN (1.0f - EPS)

// ---------- block reduction helpers (256 threads = 4 waves) ----------
static __device__ __forceinline__ float block_sum(float v, float* red4) {
#pragma unroll
  for (int m = 32; m; m >>= 1) v += __shfl_xor(v, m, 64);
  if ((threadIdx.x & 63) == 0) red4[threadIdx.x >> 6] = v;
  __syncthreads();
  v = red4[0] + red4[1] + red4[2] + red4[3];
  __syncthreads();
  return v;
}

// ---------- K1: x -> logmap0(project(x))  (row norm over 512) ----------
// layout 0: src row-major [n,512]; layout 1: gather from [B,H,S,D]
__global__ __launch_bounds__(256) void k_logmap(const float* __restrict__ s0,
                                                const float* __restrict__ s1,
                                                const float* __restrict__ s2,
                                                float* __restrict__ dst, int layout) {
  const int n = blockIdx.x, z = blockIdx.y, t = threadIdx.x;
  const float* src = (z == 0) ? s0 : ((z == 1) ? s1 : s2);
  const int e0 = t * 2;
  float2 xv;
  if (layout == 0) {
    xv = *(const float2*)&src[(size_t)n * 512 + e0];
  } else {
    const int b = n >> 9, s = n & 511, h = e0 >> 6, d = e0 & 63;
    xv = *(const float2*)&src[(((size_t)(b * 8 + h) * 512 + s) * 64 + d)];
  }
  __shared__ float red4[4];
  const float ss = block_sum(xv.x * xv.x + xv.y * xv.y, red4);
  const float r = sqrtf(fmaxf(ss, EPS2));
  float f;
  if (r >= MAXN) {
    // projected: n = (1-EPS)r/(r+EPS); stable atanh avoids 1-n cancellation
    const float at = 0.5f * logf((r * (2.0f - EPS) + EPS) / (EPS * (1.0f + r)));
    f = (1.0f + EPS) * at / r;           // includes scale/n = 1/r
  } else {
    const float at = 0.5f * logf((1.0f + r) / (1.0f - r));
    f = (1.0f + EPS) * at / r;           // r >= EPS via clamp
  }
  float2 o; o.x = f * xv.x; o.y = f * xv.y;
  *(float2*)&dst[((size_t)z * 2048 + n) * 512 + e0] = o;
}

// ---------- K2: C = A @ W^T ; A [2048,512], W [512,512] row-major ----------
__global__ __launch_bounds__(256) void k_gemm(const float* __restrict__ Abase,
                                              const float* __restrict__ W0,
                                              const float* __restrict__ W1,
                                              const float* __restrict__ W2,
                                              float* __restrict__ Cbase) {
  const int z = blockIdx.z;
  const float* A = Abase + (size_t)z * (2048 * 512);
  const float* W = (z == 0) ? W0 : ((z == 1) ? W1 : W2);
  float* C = Cbase + (size_t)z * (2048 * 512);
  __shared__ __align__(16) float As[32][68];   // k-major, pad 68 kills conflicts
  __shared__ __align__(16) float Ws[32][68];
  const int t = threadIdx.x;
  const int n0 = blockIdx.x * 64, m0 = blockIdx.y * 64;
  const int tx = t & 15, ty = t >> 4;
  const int lr = t >> 3, lk = (t & 7) * 4;
  float acc[4][4] = {};
  for (int k0 = 0; k0 < 512; k0 += 32) {
    const float4 a0 = *(const float4*)&A[(size_t)(n0 + lr) * 512 + k0 + lk];
    const float4 a1 = *(const float4*)&A[(size_t)(n0 + lr + 32) * 512 + k0 + lk];
    const float4 w0 = *(const float4*)&W[(size_t)(m0 + lr) * 512 + k0 + lk];
    const float4 w1 = *(const float4*)&W[(size_t)(m0 + lr + 32) * 512 + k0 + lk];
    __syncthreads();
    As[lk + 0][lr] = a0.x; As[lk + 1][lr] = a0.y; As[lk + 2][lr] = a0.z; As[lk + 3][lr] = a0.w;
    As[lk + 0][lr + 32] = a1.x; As[lk + 1][lr + 32] = a1.y; As[lk + 2][lr + 32] = a1.z; As[lk + 3][lr + 32] = a1.w;
    Ws[lk + 0][lr] = w0.x; Ws[lk + 1][lr] = w0.y; Ws[lk + 2][lr] = w0.z; Ws[lk + 3][lr] = w0.w;
    Ws[lk + 0][lr + 32] = w1.x; Ws[lk + 1][lr + 32] = w1.y; Ws[lk + 2][lr + 32] = w1.z; Ws[lk + 3][lr + 32] = w1.w;
    __syncthreads();
#pragma unroll
    for (int kk = 0; kk < 32; ++kk) {
      const float4 av = *(const float4*)&As[kk][ty * 4];
      const float4 wv = *(const float4*)&Ws[kk][tx * 4];
      const float a[4] = {av.x, av.y, av.z, av.w};
      const float b[4] = {wv.x, wv.y, wv.z, wv.w};
#pragma unroll
      for (int i = 0; i < 4; ++i)
#pragma unroll
        for (int j = 0; j < 4; ++j) acc[i][j] = fmaf(a[i], b[j], acc[i][j]);
    }
  }
#pragma unroll
  for (int i = 0; i < 4; ++i) {
    float4 st; st.x = acc[i][0]; st.y = acc[i][1]; st.z = acc[i][2]; st.w = acc[i][3];
    *(float4*)&C[(size_t)(n0 + ty * 4 + i) * 512 + m0 + tx * 4] = st;
  }
}

// ---------- K3: expmap0 + mobius-add bias; optional per-head project + norms ----------
__global__ __launch_bounds__(256) void k_post(const float* __restrict__ tin,
                                              const float* __restrict__ b0,
                                              const float* __restrict__ b1,
                                              const float* __restrict__ b2,
                                              float* __restrict__ o0, float* __restrict__ o1,
                                              float* __restrict__ o2,
                                              float* __restrict__ nrm0, float* __restrict__ nrm1,
                                              float* __restrict__ nrm2, int final_mode) {
  const int nrow = blockIdx.x, z = blockIdx.y, t = threadIdx.x;
  const float* tv = tin + ((size_t)z * 2048 + nrow) * 512;
  const float* bias = (z == 0) ? b0 : ((z == 1) ? b1 : b2);
  const int e0 = 2 * t;
  const float2 tp = *(const float2*)&tv[e0];
  const float2 bp = *(const float2*)&bias[e0];
  float p_tt = tp.x * tp.x + tp.y * tp.y;
  float p_tb = tp.x * bp.x + tp.y * bp.y;
  float p_bb = bp.x * bp.x + bp.y * bp.y;
#pragma unroll
  for (int m = 32; m; m >>= 1) {
    p_tt += __shfl_xor(p_tt, m, 64);
    p_tb += __shfl_xor(p_tb, m, 64);
    p_bb += __shfl_xor(p_bb, m, 64);
  }
  __shared__ float red[4][3];
  const int lane = t & 63, w = t >> 6;
  if (lane == 0) { red[w][0] = p_tt; red[w][1] = p_tb; red[w][2] = p_bb; }
  __syncthreads();
  const float s_tt = red[0][0] + red[1][0] + red[2][0] + red[3][0];
  const float s_tb = red[0][1] + red[1][1] + red[2][1] + red[3][1];
  const float s_bb = red[0][2] + red[1][2] + red[2][2] + red[3][2];
  const float tn = sqrtf(fmaxf(s_tt, EPS2));
  const float th = tanhf(tn / (1.0f + EPS));
  const float g = th / tn;
  const float rnorm = th * (sqrtf(s_tt) / tn);
  const float sr = (rnorm >= MAXN) ? (MAXN / (rnorm + EPS)) : 1.0f;
  const float gr = g * sr;
  const float rn = (rnorm * sr) * (rnorm * sr);
  const float bnorm = sqrtf(fmaxf(s_bb, EPS2));
  const float sb = (bnorm >= MAXN) ? (MAXN / (bnorm + EPS)) : 1.0f;
  const float xy = gr * sb * s_tb;
  const float yn = (sb * sb) * s_bb;
  const float Af = 1.0f + 2.0f * xy + yn;
  const float Cf = 1.0f - rn;
  const float den = 1.0f + 2.0f * xy + rn * yn + EPS;
  const float id = 1.0f / den;
  const float on_raw = (Af * Af * rn + 2.0f * Af * Cf * xy + Cf * Cf * yn) * (id * id);
  const float no = sqrtf(fmaxf(on_raw, EPS2));
  const float so = (no >= MAXN) ? (MAXN / (no + EPS)) : 1.0f;
  const float ms = id * so;
  const float ca = gr * Af * ms;
  const float cb = sb * Cf * ms;
  const float v0 = ca * tp.x + cb * bp.x;
  const float v1 = ca * tp.y + cb * bp.y;
  if (final_mode) {
    float2 o; o.x = v0; o.y = v1;
    *(float2*)&o0[(size_t)nrow * 512 + e0] = o;
    return;
  }
  float hp = v0 * v0 + v1 * v1;
#pragma unroll
  for (int m = 16; m; m >>= 1) hp += __shfl_xor(hp, m, 64);
  const float hnr = sqrtf(fmaxf(hp, EPS2));
  float sh = 1.0f;
  if (z != 2) sh = (hnr >= MAXN) ? (MAXN / (hnr + EPS)) : 1.0f;
  float* outz = (z == 0) ? o0 : ((z == 1) ? o1 : o2);
  float* nz = (z == 0) ? nrm0 : ((z == 1) ? nrm1 : nrm2);
  const int b = nrow >> 9, s = nrow & 511, h = e0 >> 6, d = e0 & 63;
  float2 o; o.x = v0 * sh; o.y = v1 * sh;
  *(float2*)&outz[(((size_t)(b * 8 + h) * 512 + s) * 64 + d)] = o;
  if ((t & 31) == 0) nz[(size_t)(b * 8 + h) * 512 + s] = hp * sh * sh;
}

// ---------- K4: -dist logits [32,512,512] ----------
__global__ __launch_bounds__(256) void k_logits(const float* __restrict__ Q,
                                                const float* __restrict__ K,
                                                const float* __restrict__ qn,
                                                const float* __restrict__ kn,
                                                float* __restrict__ attn) {
  const int bh = blockIdx.z;
  const int i0 = blockIdx.x * 64;
  const int j0 = blockIdx.y * 128;
  const float* Qb = Q + (size_t)bh * 512 * 64;
  const float* Kb = K + (size_t)bh * 512 * 64;
  __shared__ __align__(16) float q_lds[64][68];
  __shared__ __align__(16) float k_lds[128][68];
  const int t = threadIdx.x;
  const int tx = t & 15, ty = t >> 4;
  const int tx4 = tx * 4;
#pragma unroll
  for (int it = 0; it < 4; ++it) {
    const int row = it * 16 + ty;
    *(float4*)&q_lds[row][tx4] = *(const float4*)&Qb[(size_t)(i0 + row) * 64 + tx4];
  }
#pragma unroll
  for (int it = 0; it < 8; ++it) {
    const int row = it * 16 + ty;
    *(float4*)&k_lds[row][tx4] = *(const float4*)&Kb[(size_t)(j0 + row) * 64 + tx4];
  }
  __syncthreads();
  float acc[4][8] = {};
#pragma unroll
  for (int d = 0; d < 64; d += 4) {
    float4 qv[4], kv[8];
#pragma unroll
    for (int i = 0; i < 4; ++i) qv[i] = *(const float4*)&q_lds[ty * 4 + i][d];
#pragma unroll
    for (int j = 0; j < 8; ++j) kv[j] = *(const float4*)&k_lds[tx + 16 * j][d];
#pragma unroll
    for (int i = 0; i < 4; ++i)
#pragma unroll
      for (int j = 0; j < 8; ++j) {
        acc[i][j] = fmaf(qv[i].x, kv[j].x, acc[i][j]);
        acc[i][j] = fmaf(qv[i].y, kv[j].y, acc[i][j]);
        acc[i][j] = fmaf(qv[i].z, kv[j].z, acc[i][j]);
        acc[i][j] = fmaf(qv[i].w, kv[j].w, acc[i][j]);
      }
  }
  float qni[4], knj[8];
#pragma unroll
  for (int i = 0; i < 4; ++i) qni[i] = qn[(size_t)bh * 512 + i0 + ty * 4 + i];
#pragma unroll
  for (int j = 0; j < 8; ++j) knj[j] = kn[(size_t)bh * 512 + j0 + tx + 16 * j];
#pragma unroll
  for (int i = 0; i < 4; ++i)
#pragma unroll
    for (int j = 0; j < 8; ++j) {
      const float num = fmaxf(qni[i] + knj[j] - 2.0f * acc[i][j], 0.0f);
      const float den = fmaxf((1.0f - qni[i]) * (1.0f - knj[j]), EPS);
      const float wv = 2.0f * num / den + EPS;
      const float dist = logf(1.0f + wv + sqrtf(wv * (wv + 2.0f)));
      attn[((size_t)bh * 512 + i0 + ty * 4 + i) * 512 + j0 + tx + 16 * j] = -dist;
    }
}

// ---------- K5: in-place row softmax over 512 ----------
__global__ __launch_bounds__(256) void k_softmax(float* __restrict__ attn) {
  const int row = blockIdx.x, t = threadIdx.x;
  float* p = attn + (size_t)row * 512;
  const float2 x = *(const float2*)&p[2 * t];
  __shared__ float red4[4];
  float m = fmaxf(x.x, x.y);
#pragma unroll
  for (int mk = 32; mk; mk >>= 1) m = fmaxf(m, __shfl_xor(m, mk, 64));
  if ((t & 63) == 0) red4[t >> 6] = m;
  __syncthreads();
  m = fmaxf(fmaxf(red4[0], red4[1]), fmaxf(red4[2], red4[3]));
  __syncthreads();
  const float e0 = expf(x.x - m), e1 = expf(x.y - m);
  float s = e0 + e1;
#pragma unroll
  for (int mk = 32; mk; mk >>= 1) s += __shfl_xor(s, mk, 64);
  if ((t & 63) == 0) red4[t >> 6] = s;
  __syncthreads();
  s = red4[0] + red4[1] + red4[2] + red4[3];
  const float inv = 1.0f / s;
  float2 o; o.x = e0 * inv; o.y = e1 * inv;
  *(float2*)&p[2 * t] = o;
}

// ---------- K6 v2: sequential mobius scan, ONE ROW PER LANE ----------
// 64 rows/wave, 1 wave/block, 256 blocks. No cross-lane ops in the recurrence:
// ws factored as A*u so the update is 1 fma/elem; dot is 64 in-lane fma.
// v_j is wave-uniform (LDS broadcast); attn weight staged transposed in LDS.
__global__ __launch_bounds__(64) void k_scan(const float* __restrict__ V,
                                             const float* __restrict__ vn,
                                             const float* __restrict__ attnw,
                                             float* __restrict__ att) {
  __shared__ __align__(16) float v_lds[64 * 64];   // [j][d] chunk of 64 keys
  __shared__ __align__(16) float a_lds[64 * 64];   // [j][row] transposed weights
  __shared__ float vn_lds[64];
  const int blk = blockIdx.x;
  const int bh = blk >> 3;
  const int i0 = (blk & 7) * 64;
  const int r = threadIdx.x;                        // lane = local row
  const float* Vb = V + (size_t)bh * 512 * 64;
  const float* ab = attnw + ((size_t)bh * 512 + i0 + r) * 512;  // this lane's row
  const float* vnb = vn + (size_t)bh * 512;

  float u[64];
#pragma unroll
  for (int k = 0; k < 64; ++k) u[k] = 0.0f;
  float A = 1.0f;      // ws = A * u
  float xn = 0.0f;     // ||ws||^2 (projected), tracked analytically

  for (int jc = 0; jc < 512; jc += 64) {
    // stage V chunk: 64x64 floats, coalesced
#pragma unroll
    for (int it = 0; it < 16; ++it) {
      const int idx4 = it * 64 + r;
      *(float4*)&v_lds[idx4 * 4] = *(const float4*)&Vb[(size_t)jc * 64 + idx4 * 4];
    }
    // stage this lane's attn row slice, transposed into [j][row]
#pragma unroll
    for (int it = 0; it < 16; ++it) {
      const float4 w4 = *(const float4*)&ab[jc + it * 4];
      a_lds[(it * 4 + 0) * 64 + r] = w4.x;
      a_lds[(it * 4 + 1) * 64 + r] = w4.y;
      a_lds[(it * 4 + 2) * 64 + r] = w4.z;
      a_lds[(it * 4 + 3) * 64 + r] = w4.w;
    }
    vn_lds[r] = vnb[jc + r];
    __syncthreads();

#pragma unroll 2
    for (int j = 0; j < 64; ++j) {
      const float wgt = a_lds[j * 64 + r];          // per-lane weight
      const float vnj = vn_lds[j];                  // broadcast
      float4 vv[16];
#pragma unroll
      for (int q = 0; q < 16; ++q) vv[q] = *(const float4*)&v_lds[j * 64 + q * 4];
      // dot(ws, v_j) = A * dot(u, v_j): 4 independent fma chains
      float d0 = 0, d1 = 0, d2 = 0, d3 = 0;
#pragma unroll
      for (int q = 0; q < 16; q += 4) {
        d0 = fmaf(u[4 * q + 0], vv[q + 0].x, d0); d0 = fmaf(u[4 * q + 1], vv[q + 0].y, d0);
        d0 = fmaf(u[4 * q + 2], vv[q + 0].z, d0); d0 = fmaf(u[4 * q + 3], vv[q + 0].w, d0);
        d1 = fmaf(u[4 * q + 4], vv[q + 1].x, d1); d1 = fmaf(u[4 * q + 5], vv[q + 1].y, d1);
        d1 = fmaf(u[4 * q + 6], vv[q + 1].z, d1); d1 = fmaf(u[4 * q + 7], vv[q + 1].w, d1);
        d2 = fmaf(u[4 * q + 8], vv[q + 2].x, d2); d2 = fmaf(u[4 * q + 9], vv[q + 2].y, d2);
        d2 = fmaf(u[4 * q + 10], vv[q + 2].z, d2); d2 = fmaf(u[4 * q + 11], vv[q + 2].w, d2);
        d3 = fmaf(u[4 * q + 12], vv[q + 3].x, d3); d3 = fmaf(u[4 * q + 13], vv[q + 3].y, d3);
        d3 = fmaf(u[4 * q + 14], vv[q + 3].z, d3); d3 = fmaf(u[4 * q + 15], vv[q + 3].w, d3);
      }
      const float pp = A * ((d0 + d1) + (d2 + d3));
      // mobius-add scalar chain (identical math to v1)
      const float yn_raw = wgt * wgt * vnj;
      const float ny = sqrtf(fmaxf(yn_raw, EPS2));
      const float sy = (ny >= MAXN) ? (MAXN * __builtin_amdgcn_rcpf(ny + EPS)) : 1.0f;
      const float sw = sy * wgt;
      const float xy = sw * pp;
      const float yn = (sy * sy) * yn_raw;
      const float Af = 1.0f + 2.0f * xy + yn;
      const float Cf = 1.0f - xn;
      const float den = 1.0f + 2.0f * xy + xn * yn + EPS;
      float id = __builtin_amdgcn_rcpf(den);
      id = id * (2.0f - den * id);
      const float on_raw = (Af * Af * xn + 2.0f * Af * Cf * xy + Cf * Cf * yn) * (id * id);
      const float no = sqrtf(fmaxf(on_raw, EPS2));
      const float so = (no >= MAXN) ? (MAXN * __builtin_amdgcn_rcpf(no + EPS)) : 1.0f;
      const float ms = id * so;
      const float am = Af * ms;
      const float cm = Cf * sw * ms;
      // factored update: A' = A*am ; u += (cm/A') * v_j
      A = A * am;
      float rA = __builtin_amdgcn_rcpf(A);
      rA = rA * (2.0f - A * rA);
      const float cp = cm * rA;
#pragma unroll
      for (int q = 0; q < 16; ++q) {
        u[4 * q + 0] = fmaf(cp, vv[q].x, u[4 * q + 0]);
        u[4 * q + 1] = fmaf(cp, vv[q].y, u[4 * q + 1]);
        u[4 * q + 2] = fmaf(cp, vv[q].z, u[4 * q + 2]);
        u[4 * q + 3] = fmaf(cp, vv[q].w, u[4 * q + 3]);
      }
      xn = on_raw * (so * so);
    }
    __syncthreads();
  }
  // epilogue: ws = A * u -> att[bh][i0+r][:]
  float* o = att + (((size_t)bh * 512 + i0 + r) * 64);
#pragma unroll
  for (int q = 0; q < 16; ++q) {
    float4 st;
    st.x = A * u[4 * q + 0]; st.y = A * u[4 * q + 1];
    st.z = A * u[4 * q + 2]; st.w = A * u[4 * q + 3];
    *(float4*)&o[4 * q] = st;
  }
}

extern "C" void kernel_launch(void* const* d_in, const int* in_sizes, int n_in,
                              void* d_out, int out_size, void* d_ws, size_t ws_size,
                              hipStream_t stream) {
  const float* query = (const float*)d_in[0];
  const float* key_  = (const float*)d_in[1];
  const float* value = (const float*)d_in[2];
  const float* Wq = (const float*)d_in[3];
  const float* bq = (const float*)d_in[4];
  const float* Wk = (const float*)d_in[5];
  const float* bk = (const float*)d_in[6];
  const float* Wv = (const float*)d_in[7];
  const float* bv = (const float*)d_in[8];
  const float* Wo = (const float*)d_in[9];
  const float* bo = (const float*)d_in[10];
  float* ws = (float*)d_ws;
  const size_t M = 1u << 20;          // 1M floats
  float* Qb   = ws;                   // [32,512,64]
  float* Kb   = ws + 1 * M;
  float* Vb   = ws + 2 * M;
  float* qn   = ws + 3 * M;           // [32,512]
  float* kn   = qn + 16384;
  float* vn   = kn + 16384;
  float* attn = ws + 4 * M;           // [32,512,512] (8M floats)
  float* xt3  = ws + 12 * M;          // 3x [2048,512]
  float* t3   = ws + 15 * M;          // 3x [2048,512]   (peak: 72 MB)
  float* att  = ws + 12 * M;          // reuse xt3 region after QKV done
  float* xto  = ws + 13 * M;
  float* to_  = ws + 14 * M;

  k_logmap<<<dim3(2048, 3), 256, 0, stream>>>(query, key_, value, xt3, 0);
  k_gemm<<<dim3(32, 8, 3), 256, 0, stream>>>(xt3, Wq, Wk, Wv, t3);
  k_post<<<dim3(2048, 3), 256, 0, stream>>>(t3, bq, bk, bv, Qb, Kb, Vb, qn, kn, vn, 0);
  k_logits<<<dim3(8, 4, 32), 256, 0, stream>>>(Qb, Kb, qn, kn, attn);
  k_softmax<<<16384, 256, 0, stream>>>(attn);
  k_scan<<<256, 64, 0, stream>>>(Vb, vn, attn, att);
  k_logmap<<<dim3(2048, 1), 256, 0, stream>>>(att, att, att, xto, 1);
  k_gemm<<<dim3(32, 8, 1), 256, 0, stream>>>(xto, Wo, Wo, Wo, to_);
  k_post<<<dim3(2048, 1), 256, 0, stream>>>(to_, bo, bo, bo, (float*)d_out,
                                            nullptr, nullptr, nullptr, nullptr, nullptr, 1);
}

// Round 3
// 351.458 us; speedup vs baseline: 1.4899x; 1.4899x over previous
//
#include <hip/hip_runtime.h>
#include <math.h>

#define EPS  1e-5f
#define EPS2 1e-10f
#define MAXN (1.0f - EPS)

#if __has_builtin(__builtin_amdgcn_sqrtf)
static __device__ __forceinline__ float fast_sqrt(float x) { return __builtin_amdgcn_sqrtf(x); }
#else
static __device__ __forceinline__ float fast_sqrt(float x) { return sqrtf(x); }
#endif

// quad_perm DPP: cross-lane xor within quads, pure VALU (no LDS pipe)
template <int CTRL>
static __device__ __forceinline__ float qperm(float x) {
  return __int_as_float(__builtin_amdgcn_update_dpp(
      __float_as_int(x), __float_as_int(x), CTRL, 0xF, 0xF, false));
}
#define QP_XOR1 0xB1  // quad_perm [1,0,3,2]
#define QP_XOR2 0x4E  // quad_perm [2,3,0,1]

// ---------- block reduction helpers (256 threads = 4 waves) ----------
static __device__ __forceinline__ float block_sum(float v, float* red4) {
#pragma unroll
  for (int m = 32; m; m >>= 1) v += __shfl_xor(v, m, 64);
  if ((threadIdx.x & 63) == 0) red4[threadIdx.x >> 6] = v;
  __syncthreads();
  v = red4[0] + red4[1] + red4[2] + red4[3];
  __syncthreads();
  return v;
}

// ---------- K1: x -> logmap0(project(x))  (row norm over 512) ----------
__global__ __launch_bounds__(256) void k_logmap(const float* __restrict__ s0,
                                                const float* __restrict__ s1,
                                                const float* __restrict__ s2,
                                                float* __restrict__ dst, int layout) {
  const int n = blockIdx.x, z = blockIdx.y, t = threadIdx.x;
  const float* src = (z == 0) ? s0 : ((z == 1) ? s1 : s2);
  const int e0 = t * 2;
  float2 xv;
  if (layout == 0) {
    xv = *(const float2*)&src[(size_t)n * 512 + e0];
  } else {
    const int b = n >> 9, s = n & 511, h = e0 >> 6, d = e0 & 63;
    xv = *(const float2*)&src[(((size_t)(b * 8 + h) * 512 + s) * 64 + d)];
  }
  __shared__ float red4[4];
  const float ss = block_sum(xv.x * xv.x + xv.y * xv.y, red4);
  const float r = sqrtf(fmaxf(ss, EPS2));
  float f;
  if (r >= MAXN) {
    const float at = 0.5f * logf((r * (2.0f - EPS) + EPS) / (EPS * (1.0f + r)));
    f = (1.0f + EPS) * at / r;
  } else {
    const float at = 0.5f * logf((1.0f + r) / (1.0f - r));
    f = (1.0f + EPS) * at / r;
  }
  float2 o; o.x = f * xv.x; o.y = f * xv.y;
  *(float2*)&dst[((size_t)z * 2048 + n) * 512 + e0] = o;
}

// ---------- K2: C = A @ W^T ; A [2048,512], W [512,512] row-major ----------
__global__ __launch_bounds__(256) void k_gemm(const float* __restrict__ Abase,
                                              const float* __restrict__ W0,
                                              const float* __restrict__ W1,
                                              const float* __restrict__ W2,
                                              float* __restrict__ Cbase) {
  const int z = blockIdx.z;
  const float* A = Abase + (size_t)z * (2048 * 512);
  const float* W = (z == 0) ? W0 : ((z == 1) ? W1 : W2);
  float* C = Cbase + (size_t)z * (2048 * 512);
  __shared__ __align__(16) float As[32][68];
  __shared__ __align__(16) float Ws[32][68];
  const int t = threadIdx.x;
  const int n0 = blockIdx.x * 64, m0 = blockIdx.y * 64;
  const int tx = t & 15, ty = t >> 4;
  const int lr = t >> 3, lk = (t & 7) * 4;
  float acc[4][4] = {};
  for (int k0 = 0; k0 < 512; k0 += 32) {
    const float4 a0 = *(const float4*)&A[(size_t)(n0 + lr) * 512 + k0 + lk];
    const float4 a1 = *(const float4*)&A[(size_t)(n0 + lr + 32) * 512 + k0 + lk];
    const float4 w0 = *(const float4*)&W[(size_t)(m0 + lr) * 512 + k0 + lk];
    const float4 w1 = *(const float4*)&W[(size_t)(m0 + lr + 32) * 512 + k0 + lk];
    __syncthreads();
    As[lk + 0][lr] = a0.x; As[lk + 1][lr] = a0.y; As[lk + 2][lr] = a0.z; As[lk + 3][lr] = a0.w;
    As[lk + 0][lr + 32] = a1.x; As[lk + 1][lr + 32] = a1.y; As[lk + 2][lr + 32] = a1.z; As[lk + 3][lr + 32] = a1.w;
    Ws[lk + 0][lr] = w0.x; Ws[lk + 1][lr] = w0.y; Ws[lk + 2][lr] = w0.z; Ws[lk + 3][lr] = w0.w;
    Ws[lk + 0][lr + 32] = w1.x; Ws[lk + 1][lr + 32] = w1.y; Ws[lk + 2][lr + 32] = w1.z; Ws[lk + 3][lr + 32] = w1.w;
    __syncthreads();
#pragma unroll
    for (int kk = 0; kk < 32; ++kk) {
      const float4 av = *(const float4*)&As[kk][ty * 4];
      const float4 wv = *(const float4*)&Ws[kk][tx * 4];
      const float a[4] = {av.x, av.y, av.z, av.w};
      const float b[4] = {wv.x, wv.y, wv.z, wv.w};
#pragma unroll
      for (int i = 0; i < 4; ++i)
#pragma unroll
        for (int j = 0; j < 4; ++j) acc[i][j] = fmaf(a[i], b[j], acc[i][j]);
    }
  }
#pragma unroll
  for (int i = 0; i < 4; ++i) {
    float4 st; st.x = acc[i][0]; st.y = acc[i][1]; st.z = acc[i][2]; st.w = acc[i][3];
    *(float4*)&C[(size_t)(n0 + ty * 4 + i) * 512 + m0 + tx * 4] = st;
  }
}

// ---------- K3: expmap0 + mobius-add bias; optional per-head project + norms ----------
__global__ __launch_bounds__(256) void k_post(const float* __restrict__ tin,
                                              const float* __restrict__ b0,
                                              const float* __restrict__ b1,
                                              const float* __restrict__ b2,
                                              float* __restrict__ o0, float* __restrict__ o1,
                                              float* __restrict__ o2,
                                              float* __restrict__ nrm0, float* __restrict__ nrm1,
                                              float* __restrict__ nrm2, int final_mode) {
  const int nrow = blockIdx.x, z = blockIdx.y, t = threadIdx.x;
  const float* tv = tin + ((size_t)z * 2048 + nrow) * 512;
  const float* bias = (z == 0) ? b0 : ((z == 1) ? b1 : b2);
  const int e0 = 2 * t;
  const float2 tp = *(const float2*)&tv[e0];
  const float2 bp = *(const float2*)&bias[e0];
  float p_tt = tp.x * tp.x + tp.y * tp.y;
  float p_tb = tp.x * bp.x + tp.y * bp.y;
  float p_bb = bp.x * bp.x + bp.y * bp.y;
#pragma unroll
  for (int m = 32; m; m >>= 1) {
    p_tt += __shfl_xor(p_tt, m, 64);
    p_tb += __shfl_xor(p_tb, m, 64);
    p_bb += __shfl_xor(p_bb, m, 64);
  }
  __shared__ float red[4][3];
  const int lane = t & 63, w = t >> 6;
  if (lane == 0) { red[w][0] = p_tt; red[w][1] = p_tb; red[w][2] = p_bb; }
  __syncthreads();
  const float s_tt = red[0][0] + red[1][0] + red[2][0] + red[3][0];
  const float s_tb = red[0][1] + red[1][1] + red[2][1] + red[3][1];
  const float s_bb = red[0][2] + red[1][2] + red[2][2] + red[3][2];
  const float tn = sqrtf(fmaxf(s_tt, EPS2));
  const float th = tanhf(tn / (1.0f + EPS));
  const float g = th / tn;
  const float rnorm = th * (sqrtf(s_tt) / tn);
  const float sr = (rnorm >= MAXN) ? (MAXN / (rnorm + EPS)) : 1.0f;
  const float gr = g * sr;
  const float rn = (rnorm * sr) * (rnorm * sr);
  const float bnorm = sqrtf(fmaxf(s_bb, EPS2));
  const float sb = (bnorm >= MAXN) ? (MAXN / (bnorm + EPS)) : 1.0f;
  const float xy = gr * sb * s_tb;
  const float yn = (sb * sb) * s_bb;
  const float Af = 1.0f + 2.0f * xy + yn;
  const float Cf = 1.0f - rn;
  const float den = 1.0f + 2.0f * xy + rn * yn + EPS;
  const float id = 1.0f / den;
  const float on_raw = (Af * Af * rn + 2.0f * Af * Cf * xy + Cf * Cf * yn) * (id * id);
  const float no = sqrtf(fmaxf(on_raw, EPS2));
  const float so = (no >= MAXN) ? (MAXN / (no + EPS)) : 1.0f;
  const float ms = id * so;
  const float ca = gr * Af * ms;
  const float cb = sb * Cf * ms;
  const float v0 = ca * tp.x + cb * bp.x;
  const float v1 = ca * tp.y + cb * bp.y;
  if (final_mode) {
    float2 o; o.x = v0; o.y = v1;
    *(float2*)&o0[(size_t)nrow * 512 + e0] = o;
    return;
  }
  float hp = v0 * v0 + v1 * v1;
#pragma unroll
  for (int m = 16; m; m >>= 1) hp += __shfl_xor(hp, m, 64);
  const float hnr = sqrtf(fmaxf(hp, EPS2));
  float sh = 1.0f;
  if (z != 2) sh = (hnr >= MAXN) ? (MAXN / (hnr + EPS)) : 1.0f;
  float* outz = (z == 0) ? o0 : ((z == 1) ? o1 : o2);
  float* nz = (z == 0) ? nrm0 : ((z == 1) ? nrm1 : nrm2);
  const int b = nrow >> 9, s = nrow & 511, h = e0 >> 6, d = e0 & 63;
  float2 o; o.x = v0 * sh; o.y = v1 * sh;
  *(float2*)&outz[(((size_t)(b * 8 + h) * 512 + s) * 64 + d)] = o;
  if ((t & 31) == 0) nz[(size_t)(b * 8 + h) * 512 + s] = hp * sh * sh;
}

// ---------- K4: -dist logits [32,512,512] ----------
__global__ __launch_bounds__(256) void k_logits(const float* __restrict__ Q,
                                                const float* __restrict__ K,
                                                const float* __restrict__ qn,
                                                const float* __restrict__ kn,
                                                float* __restrict__ attn) {
  const int bh = blockIdx.z;
  const int i0 = blockIdx.x * 64;
  const int j0 = blockIdx.y * 128;
  const float* Qb = Q + (size_t)bh * 512 * 64;
  const float* Kb = K + (size_t)bh * 512 * 64;
  __shared__ __align__(16) float q_lds[64][68];
  __shared__ __align__(16) float k_lds[128][68];
  const int t = threadIdx.x;
  const int tx = t & 15, ty = t >> 4;
  const int tx4 = tx * 4;
#pragma unroll
  for (int it = 0; it < 4; ++it) {
    const int row = it * 16 + ty;
    *(float4*)&q_lds[row][tx4] = *(const float4*)&Qb[(size_t)(i0 + row) * 64 + tx4];
  }
#pragma unroll
  for (int it = 0; it < 8; ++it) {
    const int row = it * 16 + ty;
    *(float4*)&k_lds[row][tx4] = *(const float4*)&Kb[(size_t)(j0 + row) * 64 + tx4];
  }
  __syncthreads();
  float acc[4][8] = {};
#pragma unroll
  for (int d = 0; d < 64; d += 4) {
    float4 qv[4], kv[8];
#pragma unroll
    for (int i = 0; i < 4; ++i) qv[i] = *(const float4*)&q_lds[ty * 4 + i][d];
#pragma unroll
    for (int j = 0; j < 8; ++j) kv[j] = *(const float4*)&k_lds[tx + 16 * j][d];
#pragma unroll
    for (int i = 0; i < 4; ++i)
#pragma unroll
      for (int j = 0; j < 8; ++j) {
        acc[i][j] = fmaf(qv[i].x, kv[j].x, acc[i][j]);
        acc[i][j] = fmaf(qv[i].y, kv[j].y, acc[i][j]);
        acc[i][j] = fmaf(qv[i].z, kv[j].z, acc[i][j]);
        acc[i][j] = fmaf(qv[i].w, kv[j].w, acc[i][j]);
      }
  }
  float qni[4], knj[8];
#pragma unroll
  for (int i = 0; i < 4; ++i) qni[i] = qn[(size_t)bh * 512 + i0 + ty * 4 + i];
#pragma unroll
  for (int j = 0; j < 8; ++j) knj[j] = kn[(size_t)bh * 512 + j0 + tx + 16 * j];
#pragma unroll
  for (int i = 0; i < 4; ++i)
#pragma unroll
    for (int j = 0; j < 8; ++j) {
      const float num = fmaxf(qni[i] + knj[j] - 2.0f * acc[i][j], 0.0f);
      const float den = fmaxf((1.0f - qni[i]) * (1.0f - knj[j]), EPS);
      const float wv = 2.0f * num / den + EPS;
      const float dist = logf(1.0f + wv + sqrtf(wv * (wv + 2.0f)));
      attn[((size_t)bh * 512 + i0 + ty * 4 + i) * 512 + j0 + tx + 16 * j] = -dist;
    }
}

// ---------- K5: in-place row softmax over 512 ----------
__global__ __launch_bounds__(256) void k_softmax(float* __restrict__ attn) {
  const int row = blockIdx.x, t = threadIdx.x;
  float* p = attn + (size_t)row * 512;
  const float2 x = *(const float2*)&p[2 * t];
  __shared__ float red4[4];
  float m = fmaxf(x.x, x.y);
#pragma unroll
  for (int mk = 32; mk; mk >>= 1) m = fmaxf(m, __shfl_xor(m, mk, 64));
  if ((t & 63) == 0) red4[t >> 6] = m;
  __syncthreads();
  m = fmaxf(fmaxf(red4[0], red4[1]), fmaxf(red4[2], red4[3]));
  __syncthreads();
  const float e0 = expf(x.x - m), e1 = expf(x.y - m);
  float s = e0 + e1;
#pragma unroll
  for (int mk = 32; mk; mk >>= 1) s += __shfl_xor(s, mk, 64);
  if ((t & 63) == 0) red4[t >> 6] = s;
  __syncthreads();
  s = red4[0] + red4[1] + red4[2] + red4[3];
  const float inv = 1.0f / s;
  float2 o; o.x = e0 * inv; o.y = e1 * inv;
  *(float2*)&p[2 * t] = o;
}

// ---------- K6 v3: sequential mobius scan, 4 lanes/row (quad) ----------
// 16 rows/wave, 4 waves/block, 256 blocks -> 1024 waves = 1 per SIMD on all
// 256 CUs. Cross-lane dot via quad_perm DPP (VALU, no LDS pipe). Native
// sqrt/rcp. (sw, yn) precomputed off-chain during staging.
__global__ __launch_bounds__(256) void k_scan(const float* __restrict__ V,
                                              const float* __restrict__ vn,
                                              const float* __restrict__ attnw,
                                              float* __restrict__ att) {
  __shared__ __align__(16) float v_lds[64 * 64];      // [j][d] chunk
  __shared__ __align__(16) float swyn_lds[64 * 128];  // [j][row*2] (sw, yn)
  const int blk = blockIdx.x;
  const int bh = blk >> 3;
  const int i0 = (blk & 7) * 64;
  const int t = threadIdx.x;
  const int row_blk = t >> 2;   // 0..63: this lane's q-row within block
  const int sub = t & 3;        // 16-elem d-segment within the row's quad
  const int jseg = sub * 16;
  const float* Vb = V + (size_t)bh * 512 * 64;
  const float* vnb = vn + (size_t)bh * 512;
  const float* arow_base = attnw + ((size_t)bh * 512 + i0 + row_blk) * 512;

  float ws[16];
#pragma unroll
  for (int k = 0; k < 16; ++k) ws[k] = 0.0f;
  float xn = 0.0f;

  for (int jc = 0; jc < 512; jc += 64) {
    // ---- stage V chunk (64x64, coalesced float4) ----
#pragma unroll
    for (int it = 0; it < 4; ++it) {
      const int idx4 = it * 256 + t;
      *(float4*)&v_lds[idx4 * 4] = *(const float4*)&Vb[(size_t)jc * 64 + idx4 * 4];
    }
    // ---- load this row's 16 attn weights + vn; precompute (sw, yn) ----
    float4 aw[4], vn4[4];
#pragma unroll
    for (int it = 0; it < 4; ++it) aw[it] = *(const float4*)&arow_base[jc + jseg + it * 4];
#pragma unroll
    for (int it = 0; it < 4; ++it) vn4[it] = *(const float4*)&vnb[jc + jseg + it * 4];
#pragma unroll
    for (int it = 0; it < 4; ++it) {
      const float wq[4] = {aw[it].x, aw[it].y, aw[it].z, aw[it].w};
      const float vq[4] = {vn4[it].x, vn4[it].y, vn4[it].z, vn4[it].w};
#pragma unroll
      for (int e = 0; e < 4; ++e) {
        const float wgt = wq[e];
        const float ynr = wgt * wgt * vq[e];
        const float ny = fast_sqrt(fmaxf(ynr, EPS2));
        const float sy = (ny >= MAXN) ? (MAXN * __builtin_amdgcn_rcpf(ny + EPS)) : 1.0f;
        const int j = jseg + it * 4 + e;
        float2 p; p.x = sy * wgt; p.y = (sy * sy) * ynr;
        *(float2*)&swyn_lds[j * 128 + row_blk * 2] = p;
      }
    }
    __syncthreads();

    // ---- 64 sequential mobius steps ----
#pragma unroll 4
    for (int j = 0; j < 64; ++j) {
      const float2 sy2 = *(const float2*)&swyn_lds[j * 128 + row_blk * 2];
      const float4 v0 = *(const float4*)&v_lds[j * 64 + jseg + 0];
      const float4 v1 = *(const float4*)&v_lds[j * 64 + jseg + 4];
      const float4 v2 = *(const float4*)&v_lds[j * 64 + jseg + 8];
      const float4 v3 = *(const float4*)&v_lds[j * 64 + jseg + 12];
      // partial dot over this lane's 16 elems (4 independent chains)
      float d0 = ws[0] * v0.x;
      d0 = fmaf(ws[1], v0.y, d0); d0 = fmaf(ws[2], v0.z, d0); d0 = fmaf(ws[3], v0.w, d0);
      float d1 = ws[4] * v1.x;
      d1 = fmaf(ws[5], v1.y, d1); d1 = fmaf(ws[6], v1.z, d1); d1 = fmaf(ws[7], v1.w, d1);
      float d2 = ws[8] * v2.x;
      d2 = fmaf(ws[9], v2.y, d2); d2 = fmaf(ws[10], v2.z, d2); d2 = fmaf(ws[11], v2.w, d2);
      float d3 = ws[12] * v3.x;
      d3 = fmaf(ws[13], v3.y, d3); d3 = fmaf(ws[14], v3.z, d3); d3 = fmaf(ws[15], v3.w, d3);
      float d = (d0 + d1) + (d2 + d3);
      d += qperm<QP_XOR1>(d);
      d += qperm<QP_XOR2>(d);          // full dot(ws, v_j) in every lane of the quad
      const float sw = sy2.x, yn = sy2.y;
      const float xy = sw * d;
      const float Cf = 1.0f - xn;
      const float den = fmaf(2.0f, xy, fmaf(xn, yn, 1.0f + EPS));
      const float Af = fmaf(2.0f, xy, 1.0f + yn);
      const float id = __builtin_amdgcn_rcpf(den);
      const float AfCf = Af * Cf;
      const float onn = fmaf(Af * Af, xn, fmaf(2.0f * xy, AfCf, (Cf * Cf) * yn));
      const float on_raw = onn * (id * id);
      const float no = fast_sqrt(fmaxf(on_raw, EPS2));
      const float so = (no >= MAXN) ? (MAXN * __builtin_amdgcn_rcpf(no + EPS)) : 1.0f;
      const float ms = id * so;
      const float am = Af * ms;
      const float cm = (Cf * sw) * ms;
      ws[0] = fmaf(am, ws[0], cm * v0.x); ws[1] = fmaf(am, ws[1], cm * v0.y);
      ws[2] = fmaf(am, ws[2], cm * v0.z); ws[3] = fmaf(am, ws[3], cm * v0.w);
      ws[4] = fmaf(am, ws[4], cm * v1.x); ws[5] = fmaf(am, ws[5], cm * v1.y);
      ws[6] = fmaf(am, ws[6], cm * v1.z); ws[7] = fmaf(am, ws[7], cm * v1.w);
      ws[8] = fmaf(am, ws[8], cm * v2.x); ws[9] = fmaf(am, ws[9], cm * v2.y);
      ws[10] = fmaf(am, ws[10], cm * v2.z); ws[11] = fmaf(am, ws[11], cm * v2.w);
      ws[12] = fmaf(am, ws[12], cm * v3.x); ws[13] = fmaf(am, ws[13], cm * v3.y);
      ws[14] = fmaf(am, ws[14], cm * v3.z); ws[15] = fmaf(am, ws[15], cm * v3.w);
      xn = on_raw * (so * so);
    }
    __syncthreads();
  }
  // epilogue: this lane's 16-elem segment of its row
  float* o = att + (((size_t)bh * 512 + i0 + row_blk) * 64 + jseg);
#pragma unroll
  for (int q = 0; q < 4; ++q) {
    float4 st;
    st.x = ws[4 * q + 0]; st.y = ws[4 * q + 1];
    st.z = ws[4 * q + 2]; st.w = ws[4 * q + 3];
    *(float4*)&o[4 * q] = st;
  }
}

extern "C" void kernel_launch(void* const* d_in, const int* in_sizes, int n_in,
                              void* d_out, int out_size, void* d_ws, size_t ws_size,
                              hipStream_t stream) {
  const float* query = (const float*)d_in[0];
  const float* key_  = (const float*)d_in[1];
  const float* value = (const float*)d_in[2];
  const float* Wq = (const float*)d_in[3];
  const float* bq = (const float*)d_in[4];
  const float* Wk = (const float*)d_in[5];
  const float* bk = (const float*)d_in[6];
  const float* Wv = (const float*)d_in[7];
  const float* bv = (const float*)d_in[8];
  const float* Wo = (const float*)d_in[9];
  const float* bo = (const float*)d_in[10];
  float* ws = (float*)d_ws;
  const size_t M = 1u << 20;          // 1M floats
  float* Qb   = ws;                   // [32,512,64]
  float* Kb   = ws + 1 * M;
  float* Vb   = ws + 2 * M;
  float* qn   = ws + 3 * M;           // [32,512]
  float* kn   = qn + 16384;
  float* vn   = kn + 16384;
  float* attn = ws + 4 * M;           // [32,512,512] (8M floats)
  float* xt3  = ws + 12 * M;          // 3x [2048,512]
  float* t3   = ws + 15 * M;          // 3x [2048,512]   (peak: 72 MB)
  float* att  = ws + 12 * M;          // reuse xt3 region after QKV done
  float* xto  = ws + 13 * M;
  float* to_  = ws + 14 * M;

  k_logmap<<<dim3(2048, 3), 256, 0, stream>>>(query, key_, value, xt3, 0);
  k_gemm<<<dim3(32, 8, 3), 256, 0, stream>>>(xt3, Wq, Wk, Wv, t3);
  k_post<<<dim3(2048, 3), 256, 0, stream>>>(t3, bq, bk, bv, Qb, Kb, Vb, qn, kn, vn, 0);
  k_logits<<<dim3(8, 4, 32), 256, 0, stream>>>(Qb, Kb, qn, kn, attn);
  k_softmax<<<16384, 256, 0, stream>>>(attn);
  k_scan<<<256, 256, 0, stream>>>(Vb, vn, attn, att);
  k_logmap<<<dim3(2048, 1), 256, 0, stream>>>(att, att, att, xto, 1);
  k_gemm<<<dim3(32, 8, 1), 256, 0, stream>>>(xto, Wo, Wo, Wo, to_);
  k_post<<<dim3(2048, 1), 256, 0, stream>>>(to_, bo, bo, bo, (float*)d_out,
                                            nullptr, nullptr, nullptr, nullptr, nullptr, 1);
}